// Round 6
// baseline (1331.724 us; speedup 1.0000x reference)
//
#include <hip/hip_runtime.h>
#include <math.h>

#define V 50257
#define B 2
#define T 2048
#define D 768
#define H 12
#define HD 64
#define L 4
#define D3 (3*D)
#define D4 (4*D)
#define NTOK (B*T)          // 4096
#define EPS 1e-5f

typedef __bf16 v8bf __attribute__((ext_vector_type(8)));
typedef __bf16 v4bf __attribute__((ext_vector_type(4)));
typedef unsigned short v8us __attribute__((ext_vector_type(8)));
typedef float  v4f  __attribute__((ext_vector_type(4)));

#define GAS(p) ((const __attribute__((address_space(1))) void*)(p))
#define LAS(p) ((__attribute__((address_space(3))) void*)(p))

// swizzled LDS tile addressing: 64-elem (128B) rows, 16B chunks, chunk ^= row&7.
#define LIDX(row, chunk) ((row)*64 + ((((chunk) ^ ((row)&7)))<<3))

#define SBAR() asm volatile("s_barrier" ::: "memory")

// fast erf (Abramowitz-Stegun 7.1.26, max abs err 1.5e-7) for GELU
__device__ __forceinline__ float gelu_fast(float x) {
    float z  = fabsf(x) * 0.70710678118f;
    float tt = 1.f / (1.f + 0.3275911f * z);
    float poly = tt * (0.254829592f + tt * (-0.284496736f + tt * (1.421413741f +
                 tt * (-1.453152027f + tt * 1.061405429f))));
    float er = 1.f - poly * __expf(-z * z);
    er = (x < 0.f) ? -er : er;
    return 0.5f * x * (1.f + er);
}

// ------- prep: embed (vectorized) + ALL-layer weight convert+transpose ------
__global__ __launch_bounds__(256) void prep_kernel(
        const int* __restrict__ idx, const float* __restrict__ wte,
        const float* __restrict__ wpe, float* __restrict__ x,
        const float* __restrict__ aw_all,  const float* __restrict__ pw_all,
        const float* __restrict__ fw_all,  const float* __restrict__ fpw_all,
        __bf16* __restrict__ awt_all, __bf16* __restrict__ pwt_all,
        __bf16* __restrict__ fwt_all, __bf16* __restrict__ fpwt_all) {
    int bid = blockIdx.x;
    if (bid < 3072) {
        int e = (bid * 256 + threadIdx.x) * 4;      // 3072*256*4 = NTOK*D exactly
        int pos = e / D;
        int d   = e - pos * D;
        int t   = pos & (T - 1);
        int tok = idx[pos];
        const float4 a  = *(const float4*)(wte + (size_t)tok * D + d);
        const float4 p4 = *(const float4*)(wpe + (size_t)t * D + d);
        float4 r; r.x = a.x + p4.x; r.y = a.y + p4.y; r.z = a.z + p4.z; r.w = a.w + p4.w;
        *(float4*)(x + e) = r;
        return;
    }
    bid -= 3072;
    const int l = bid / 6912; bid -= l * 6912;
    const float* W; __bf16* Wt; int K, N, bx, by;
    if (bid < 1728)      {             W = aw_all  + (size_t)l * D  * D3; Wt = awt_all  + (size_t)l * D3 * D;  K = D;  N = D3; bx = bid % 72; by = bid / 72; }
    else if (bid < 2304) { bid -= 1728; W = pw_all  + (size_t)l * D  * D;  Wt = pwt_all  + (size_t)l * D  * D;  K = D;  N = D;  bx = bid % 24; by = bid / 24; }
    else if (bid < 4608) { bid -= 2304; W = fw_all  + (size_t)l * D  * D4; Wt = fwt_all  + (size_t)l * D4 * D;  K = D;  N = D4; bx = bid % 96; by = bid / 96; }
    else                 { bid -= 4608; W = fpw_all + (size_t)l * D4 * D;  Wt = fpwt_all + (size_t)l * D  * D4; K = D4; N = D;  bx = bid % 24; by = bid / 24; }
    __shared__ float t[32][33];
    const int n0 = bx * 32, k0 = by * 32;
    const int tx = threadIdx.x & 31, ty = threadIdx.x >> 5;
    #pragma unroll
    for (int p = 0; p < 4; ++p)
        t[ty + 8 * p][tx] = W[(size_t)(k0 + ty + 8 * p) * N + n0 + tx];
    __syncthreads();
    #pragma unroll
    for (int p = 0; p < 4; ++p)
        Wt[(size_t)(n0 + ty + 8 * p) * K + k0 + tx] = (__bf16)t[tx][ty + 8 * p];
}

// ---------------- layernorm: fp32 in, bf16 out ----------------
__global__ __launch_bounds__(256) void ln_kernel(const float* __restrict__ X,
                                                 const float* __restrict__ w,
                                                 const float* __restrict__ b,
                                                 __bf16* __restrict__ Y,
                                                 int src_mul, int src_off) {
    int srow = blockIdx.x * src_mul + src_off;
    const float* xr = X + (size_t)srow * D;
    float v[3];
    float s = 0.f, s2 = 0.f;
    #pragma unroll
    for (int j = 0; j < 3; ++j) {
        v[j] = xr[threadIdx.x + 256 * j];
        s += v[j];
        s2 += v[j] * v[j];
    }
    #pragma unroll
    for (int off = 32; off; off >>= 1) {
        s  += __shfl_xor(s, off);
        s2 += __shfl_xor(s2, off);
    }
    __shared__ float ss[4], ss2[4];
    int wave = threadIdx.x >> 6, lane = threadIdx.x & 63;
    if (lane == 0) { ss[wave] = s; ss2[wave] = s2; }
    __syncthreads();
    s  = ss[0] + ss[1] + ss[2] + ss[3];
    s2 = ss2[0] + ss2[1] + ss2[2] + ss2[3];
    float mu  = s * (1.f / D);
    float var = s2 * (1.f / D) - mu * mu;
    float rs  = rsqrtf(var + EPS);
    __bf16* yr = Y + (size_t)blockIdx.x * D;
    #pragma unroll
    for (int j = 0; j < 3; ++j) {
        int c = threadIdx.x + 256 * j;
        yr[c] = (__bf16)((v[j] - mu) * rs * w[c] + b[c]);
    }
}

// ---- bf16 MFMA GEMM 128x64-tile, BK=32, dbuf + counted vmcnt ---------------
// TLP-first: 24 KB LDS/block -> 6 blocks/CU (fc grid 1536 = 6/CU, 24 waves,
// 75% occupancy vs 32% at 128x128). Stage = 3 gload_lds/thread; loop waits
// only the oldest stage (vmcnt(3)) so next-tile loads span the barrier.
template<bool DOGELU>
__global__ __launch_bounds__(256) void gemm_bt(const __bf16* __restrict__ A,
                                               const __bf16* __restrict__ Wt,
                                               const float* __restrict__ bias,
                                               __bf16* __restrict__ Cout,
                                               int N, int K) {
    __shared__ __align__(16) __bf16 sm[12288];   // 2 x (A 4096 | B 2048) = 24 KB
    const int tid  = threadIdx.x;
    const int w    = tid >> 6;
    const int lane = tid & 63;

    // XCD-chunked work remap (nwg % 8 == 0 for all our grids)
    int fid = blockIdx.y * gridDim.x + blockIdx.x;
    const int nwg = gridDim.x * gridDim.y;
    fid = (fid & 7) * (nwg >> 3) + (fid >> 3);
    const int row0 = (fid / gridDim.x) * 128;
    const int col0 = (fid % gridDim.x) * 64;

    const int srow = ((tid >> 6) & 3) * 16 + (tid & 15);
    const int sk   = ((tid >> 4) & 3) * 8;
    const __bf16* gA0 = A  + (size_t)(row0 + srow) * K + sk;
    const __bf16* gA1 = gA0 + (size_t)64 * K;
    const __bf16* gB0 = Wt + (size_t)(col0 + srow) * K + sk;   // 64 rows exactly

    auto stage = [&](int bsel) {
        __bf16* dst = sm + bsel * 6144;
        __builtin_amdgcn_global_load_lds(GAS(gA0), LAS(dst + (size_t)tid * 8), 16, 0, 0);
        __builtin_amdgcn_global_load_lds(GAS(gA1), LAS(dst + (size_t)(tid + 256) * 8), 16, 0, 0);
        __builtin_amdgcn_global_load_lds(GAS(gB0), LAS(dst + 4096 + (size_t)tid * 8), 16, 0, 0);
        gA0 += 32; gA1 += 32; gB0 += 32;
    };

    const int wr = w >> 1, wc = w & 1;
    const __bf16* rA = sm + wr * 2048 + lane * 8;
    const __bf16* rB = sm + 4096 + wc * 1024 + lane * 8;

    const int nt = K >> 5;          // 24 for K=768
    stage(0);                       // tile 0 -> buf 0 (3 loads in flight)

    v4f acc[4][2] = {};
    for (int t = 0; t < nt; ++t) {
        const int cb = (t & 1) * 6144;
        if (t + 1 < nt) {
            stage((t + 1) & 1);     // 6 in flight
            asm volatile("s_waitcnt vmcnt(3)\n\ts_barrier" ::: "memory");
        } else {
            asm volatile("s_waitcnt vmcnt(0)\n\ts_barrier" ::: "memory");
        }
        v8bf af[4], bfr[2];
        #pragma unroll
        for (int i = 0; i < 4; ++i) af[i]  = *(const v8bf*)(rA + cb + i * 512);
        #pragma unroll
        for (int j = 0; j < 2; ++j) bfr[j] = *(const v8bf*)(rB + cb + j * 512);
        #pragma unroll
        for (int i = 0; i < 4; ++i)
            #pragma unroll
            for (int j = 0; j < 2; ++j)
                acc[i][j] = __builtin_amdgcn_mfma_f32_16x16x32_bf16(af[i], bfr[j], acc[i][j], 0, 0, 0);
        SBAR();                     // buf (t&1) free for reuse at t+1
    }

    // ---- epilogue: bias/gelu -> bf16 -> LDS (swizzled) -> coalesced stores ----
    const int er = (lane >> 4) * 4;
    const int ec = lane & 15;
    #pragma unroll
    for (int j = 0; j < 2; ++j) {
        const int col = wc * 32 + j * 16 + ec;
        const float bval = bias[col0 + col];
        const int chunk = col >> 3, ce = col & 7;
        #pragma unroll
        for (int i = 0; i < 4; ++i) {
            const int rowb = wr * 64 + i * 16 + er;
            #pragma unroll
            for (int rr = 0; rr < 4; ++rr) {
                float vv = acc[i][j][rr] + bval;
                if (DOGELU) vv = gelu_fast(vv);
                sm[LIDX(rowb + rr, chunk) + ce] = (__bf16)vv;   // 128x64 C tile, 16 KB
            }
        }
    }
    __syncthreads();
    #pragma unroll
    for (int c = 0; c < 4; ++c) {
        const int chunkid = tid + c * 256;         // 0..1023
        const int row = chunkid >> 3;
        const int cc  = chunkid & 7;
        *(v8us*)(void*)(Cout + (size_t)(row0 + row) * N + col0 + cc * 8) =
            *(const v8us*)(const void*)(sm + LIDX(row, cc));
    }
}

// ---- bf16 MFMA GEMM 64x64, BK=64, 3-deep ring + counted vmcnt (fp32+res) ---
__global__ __launch_bounds__(256) void gemm64(const __bf16* __restrict__ A,
                                              const __bf16* __restrict__ Wt,
                                              const float* __restrict__ bias,
                                              const float* __restrict__ res,
                                              float* __restrict__ Cout,
                                              int N, int K) {
    __shared__ __align__(16) __bf16 sm[24576];   // 3 x (A 4096 | B 4096) = 48 KB
    const int tid  = threadIdx.x;
    const int w    = tid >> 6;
    const int lane = tid & 63;

    int fid = blockIdx.y * gridDim.x + blockIdx.x;
    const int nwg = gridDim.x * gridDim.y;
    fid = (fid & 7) * (nwg >> 3) + (fid >> 3);
    const int row0 = (fid / gridDim.x) * 64;
    const int col0 = (fid % gridDim.x) * 64;

    const int srow = ((tid >> 7) & 3) * 16 + (tid & 15);
    const int sk   = ((tid >> 4) & 7) * 8;
    const __bf16* gA0 = A  + (size_t)(row0 + srow) * K + sk;
    const __bf16* gA1 = gA0 + (size_t)32 * K;
    const __bf16* gB0 = Wt + (size_t)(col0 + srow) * K + sk;
    const __bf16* gB1 = gB0 + (size_t)32 * K;

    auto stage = [&](int bsel) {
        __bf16* dst = sm + bsel * 8192;
        __builtin_amdgcn_global_load_lds(GAS(gA0), LAS(dst + (size_t)tid * 8), 16, 0, 0);
        __builtin_amdgcn_global_load_lds(GAS(gA1), LAS(dst + (size_t)(tid + 256) * 8), 16, 0, 0);
        __builtin_amdgcn_global_load_lds(GAS(gB0), LAS(dst + 4096 + (size_t)tid * 8), 16, 0, 0);
        __builtin_amdgcn_global_load_lds(GAS(gB1), LAS(dst + 4096 + (size_t)(tid + 256) * 8), 16, 0, 0);
        gA0 += 64; gA1 += 64; gB0 += 64; gB1 += 64;
    };

    const int wr = w >> 1, wc = w & 1;
    const __bf16* rA = sm + wr * 2048 + lane * 8;
    const __bf16* rB = sm + 4096 + wc * 2048 + lane * 8;

    const int nt = K >> 6;          // 12 (proj) / 48 (fcp)
    stage(0); stage(1);

    v4f acc[2][2] = {};
    for (int t = 0; t < nt; ++t) {
        const int cb = (t % 3) * 8192;
        if (t + 2 < nt) {
            stage((t + 2) % 3);
            asm volatile("s_waitcnt vmcnt(8)\n\ts_barrier" ::: "memory");
        } else if (t + 1 < nt) {
            asm volatile("s_waitcnt vmcnt(4)\n\ts_barrier" ::: "memory");
        } else {
            asm volatile("s_waitcnt vmcnt(0)\n\ts_barrier" ::: "memory");
        }
        #pragma unroll
        for (int h = 0; h < 2; ++h) {
            v8bf af[2], bfr[2];
            #pragma unroll
            for (int i = 0; i < 2; ++i) af[i]  = *(const v8bf*)(rA + cb + i * 1024 + h * 512);
            #pragma unroll
            for (int j = 0; j < 2; ++j) bfr[j] = *(const v8bf*)(rB + cb + j * 1024 + h * 512);
            #pragma unroll
            for (int i = 0; i < 2; ++i)
                #pragma unroll
                for (int j = 0; j < 2; ++j)
                    acc[i][j] = __builtin_amdgcn_mfma_f32_16x16x32_bf16(af[i], bfr[j], acc[i][j], 0, 0, 0);
        }
        SBAR();
    }

    // ---- epilogue: acc+bias -> LDS fp32 (swizzled) -> coalesced res+store ----
    float* smf = (float*)sm;        // 64x64 fp32 = 16 KB
    const int er = (lane >> 4) * 4;
    const int ec = lane & 15;
    #pragma unroll
    for (int j = 0; j < 2; ++j) {
        const int col = wc * 32 + j * 16 + ec;
        const float bval = bias[col0 + col];
        #pragma unroll
        for (int i = 0; i < 2; ++i) {
            #pragma unroll
            for (int rr = 0; rr < 4; ++rr) {
                const int row = wr * 32 + i * 16 + er + rr;
                smf[row * 64 + (col ^ ((row & 3) << 4))] = acc[i][j][rr] + bval;
            }
        }
    }
    __syncthreads();
    #pragma unroll
    for (int c = 0; c < 4; ++c) {
        const int chunkid = tid + c * 256;         // 0..1023
        const int row = chunkid >> 4;
        const int c0  = (chunkid & 15) * 4;
        float4 vv = *(const float4*)(smf + row * 64 + (c0 ^ ((row & 3) << 4)));
        const float4 rv = *(const float4*)(res + (size_t)(row0 + row) * N + col0 + c0);
        vv.x += rv.x; vv.y += rv.y; vv.z += rv.z; vv.w += rv.w;
        *(float4*)(Cout + (size_t)(row0 + row) * N + col0 + c0) = vv;
    }
}

// ---------------- MFMA flash attention: 64 q-rows/block, swapped QK^T -------
__global__ __launch_bounds__(256) void attn_mfma(const __bf16* __restrict__ qkv,
                                                 __bf16* __restrict__ y) {
    __shared__ __align__(16) __bf16 Qs[4096];
    __shared__ __align__(16) __bf16 Ks[4096];
    __shared__ __align__(16) __bf16 Vt[4096];
    __shared__ __align__(16) __bf16 Ps[4][1024];

    const int tid  = threadIdx.x;
    const int w    = tid >> 6;
    const int lane = tid & 63;
    const int quad = lane >> 4;
    const int l4   = lane & 15;

    // XCD-chunked remap
    int fid = blockIdx.x;
    const int nwg = gridDim.x;
    fid = (fid & 7) * (nwg >> 3) + (fid >> 3);

    const int qt = 31 - (fid & 31);              // big tiles first
    const int bh = fid >> 5;
    const int b  = bh / H;
    const int h  = bh - b * H;
    const int q0 = qt * 64;

    const __bf16* base = qkv + (size_t)(b * T) * D3 + h * HD;

    // stage Q tile (64 rows), swizzled
    {
        int c = tid;
        #pragma unroll
        for (int rep = 0; rep < 2; ++rep, c += 256) {
            int row = c >> 3, ch = c & 7;
            v8us v = *(const v8us*)(const void*)(base + (size_t)(q0 + row) * D3 + ch * 8);
            *(v8us*)(void*)(Qs + LIDX(row, ch)) = v;
        }
    }

    const int krow = tid >> 3, kch = tid & 7;
    const int vkp = tid & 31, vdc = tid >> 5;
    const __bf16* kp0 = base + D     + (size_t)krow * D3 + kch * 8;
    const __bf16* kp1 = kp0 + (size_t)32 * D3;
    const __bf16* vp0 = base + 2 * D + (size_t)(2 * vkp) * D3 + vdc * 8;
    const __bf16* vp1 = vp0 + D3;

    v8us kr0 = *(const v8us*)(const void*)kp0;
    v8us kr1 = *(const v8us*)(const void*)kp1;
    v8us vr0 = *(const v8us*)(const void*)vp0;
    v8us vr1 = *(const v8us*)(const void*)vp1;

    float m_local = -INFINITY;      // running max for q = q0 + w*16 + l4
    v4f o[4] = {};
    v4f sacc = {};                  // softmax denominators via ones-MFMA
    v8bf qf[2];
    v8bf vones;
    #pragma unroll
    for (int i = 0; i < 8; ++i) vones[i] = (__bf16)1.0f;

    const int nt = qt + 1;
    const size_t adv = (size_t)64 * D3;
    const int qrow = q0 + w * 16 + l4;

    for (int kt = 0; kt < nt; ++kt) {
        const int k0 = kt * 64;
        // ---- write prefetched K tile (natural rows, swizzled) ----
        *(v8us*)(void*)(Ks + LIDX(krow, kch))      = kr0;
        *(v8us*)(void*)(Ks + LIDX(krow + 32, kch)) = kr1;
        // ---- write prefetched V transposed: Vt[dim][key], swizzled ----
        #pragma unroll
        for (int j = 0; j < 8; ++j) {
            int dim = vdc * 8 + j;
            int idx = dim * 64 + ((((vkp >> 2) ^ (dim & 7))) << 3) + ((vkp & 3) << 1);
            *(unsigned int*)(void*)(Vt + idx) =
                ((unsigned int)vr1[j] << 16) | (unsigned int)vr0[j];
        }
        __syncthreads();

        if (kt == 0) {
            #pragma unroll
            for (int kh = 0; kh < 2; ++kh)
                qf[kh] = *(const v8bf*)(Qs + LIDX(w * 16 + l4, kh * 4 + quad));
        }
        // ---- issue next tile's global loads (latency hidden by compute) ----
        if (kt + 1 < nt) {
            kp0 += adv; kp1 += adv; vp0 += adv; vp1 += adv;
            kr0 = *(const v8us*)(const void*)kp0;
            kr1 = *(const v8us*)(const void*)kp1;
            vr0 = *(const v8us*)(const void*)vp0;
            vr1 = *(const v8us*)(const void*)vp1;
        }

        // ---- S^T = K Q^T : lane holds keys (jb*16 + quad*4 + rg) for q=l4 ----
        v4f s[4] = {};
        __builtin_amdgcn_s_setprio(1);
        #pragma unroll
        for (int kh = 0; kh < 2; ++kh) {
            #pragma unroll
            for (int jb = 0; jb < 4; ++jb) {
                v8bf bk = *(const v8bf*)(Ks + LIDX(jb * 16 + l4, kh * 4 + quad));
                s[jb] = __builtin_amdgcn_mfma_f32_16x16x32_bf16(bk, qf[kh], s[jb], 0, 0, 0);
            }
        }
        __builtin_amdgcn_s_setprio(0);

        // ---- online softmax, lane-local row ----
        float sv[4][4];
        float mx = -INFINITY;
        #pragma unroll
        for (int jb = 0; jb < 4; ++jb) {
            #pragma unroll
            for (int rg = 0; rg < 4; ++rg) {
                float vvv = s[jb][rg] * 0.125f;
                if (k0 + jb * 16 + quad * 4 + rg > qrow) vvv = -INFINITY;
                sv[jb][rg] = vvv;
                mx = fmaxf(mx, vvv);
            }
        }
        mx = fmaxf(mx, __shfl_xor(mx, 16));
        mx = fmaxf(mx, __shfl_xor(mx, 32));
        // defer-max: rescale only when some lane's max grew past m_local + 8
        if (!__all(mx <= m_local + 8.f)) {
            const float mnew    = fmaxf(m_local, mx);
            const float alpha_l = __expf(m_local - mnew);
            m_local = mnew;
            float a4[4];
            #pragma unroll
            for (int r = 0; r < 4; ++r) a4[r] = __shfl(alpha_l, quad * 4 + r);
            #pragma unroll
            for (int r = 0; r < 4; ++r) {
                sacc[r] *= a4[r];
                #pragma unroll
                for (int db = 0; db < 4; ++db) o[db][r] *= a4[r];
            }
        }
        // ---- P -> per-wave LDS (packed b64 stores, swizzled) ----
        #pragma unroll
        for (int jb = 0; jb < 4; ++jb) {
            v4bf pk;
            #pragma unroll
            for (int rg = 0; rg < 4; ++rg)
                pk[rg] = (__bf16)__expf(sv[jb][rg] - m_local);
            *(v4bf*)(void*)(&Ps[w][LIDX(l4, jb * 2 + (quad >> 1)) + ((quad & 1) << 2)]) = pk;
        }
        // ---- O += P V ; denom += P 1 ----
        __builtin_amdgcn_s_setprio(1);
        #pragma unroll
        for (int kh = 0; kh < 2; ++kh) {
            v8bf ap = *(const v8bf*)(&Ps[w][LIDX(l4, kh * 4 + quad)]);
            sacc = __builtin_amdgcn_mfma_f32_16x16x32_bf16(ap, vones, sacc, 0, 0, 0);
            #pragma unroll
            for (int db = 0; db < 4; ++db) {
                v8bf bv = *(const v8bf*)(Vt + LIDX(db * 16 + l4, kh * 4 + quad));
                o[db] = __builtin_amdgcn_mfma_f32_16x16x32_bf16(ap, bv, o[db], 0, 0, 0);
            }
        }
        __builtin_amdgcn_s_setprio(0);
        __syncthreads();
    }

    // ---- epilogue ----
    #pragma unroll
    for (int db = 0; db < 4; ++db) {
        #pragma unroll
        for (int r = 0; r < 4; ++r) {
            const int q = q0 + w * 16 + quad * 4 + r;
            y[(size_t)(b * T + q) * D + h * HD + db * 16 + l4] =
                (__bf16)(o[db][r] / sacc[r]);
        }
    }
}

// ---------------- lm head: both batch rows per wte pass ---------------------
__global__ __launch_bounds__(256) void logits_kernel(const __bf16* __restrict__ xf,
                                                     const float* __restrict__ wte,
                                                     float* __restrict__ out) {
    int wave = threadIdx.x >> 6;
    int lane = threadIdx.x & 63;
    int v = blockIdx.x * 4 + wave;
    if (v >= V) return;
    const float4* wr = (const float4*)(wte + (size_t)v * D);   // 192 chunks
    const v4bf*   x0 = (const v4bf*)(xf);
    const v4bf*   x1 = (const v4bf*)(xf + D);
    float s0 = 0.f, s1 = 0.f;
    #pragma unroll
    for (int j = 0; j < 3; ++j) {
        float4 wv = wr[lane + 64 * j];
        v4bf a0 = x0[lane + 64 * j];
        v4bf a1 = x1[lane + 64 * j];
        s0 = fmaf(wv.x, (float)a0[0], s0); s0 = fmaf(wv.y, (float)a0[1], s0);
        s0 = fmaf(wv.z, (float)a0[2], s0); s0 = fmaf(wv.w, (float)a0[3], s0);
        s1 = fmaf(wv.x, (float)a1[0], s1); s1 = fmaf(wv.y, (float)a1[1], s1);
        s1 = fmaf(wv.z, (float)a1[2], s1); s1 = fmaf(wv.w, (float)a1[3], s1);
    }
    #pragma unroll
    for (int off = 32; off; off >>= 1) {
        s0 += __shfl_xor(s0, off);
        s1 += __shfl_xor(s1, off);
    }
    if (lane == 0) { out[v] = s0; out[V + v] = s1; }
}

extern "C" void kernel_launch(void* const* d_in, const int* in_sizes, int n_in,
                              void* d_out, int out_size, void* d_ws, size_t ws_size,
                              hipStream_t stream) {
    const int*   idx    = (const int*)  d_in[0];
    const float* wte    = (const float*)d_in[1];
    const float* wpe    = (const float*)d_in[2];
    const float* ln1_w  = (const float*)d_in[3];
    const float* ln1_b  = (const float*)d_in[4];
    const float* attn_w = (const float*)d_in[5];
    const float* attn_b = (const float*)d_in[6];
    const float* proj_w = (const float*)d_in[7];
    const float* proj_b = (const float*)d_in[8];
    const float* ln2_w  = (const float*)d_in[9];
    const float* ln2_b  = (const float*)d_in[10];
    const float* fc_w   = (const float*)d_in[11];
    const float* fc_b   = (const float*)d_in[12];
    const float* fcp_w  = (const float*)d_in[13];
    const float* fcp_b  = (const float*)d_in[14];
    const float* lnf_w  = (const float*)d_in[15];
    const float* lnf_b  = (const float*)d_in[16];
    float* out = (float*)d_out;

    char* ws = (char*)d_ws;
    float*  x    = (float*)ws;  ws += (size_t)NTOK * D  * 4;       // residual stream fp32
    __bf16* qkvb = (__bf16*)ws;                                     // [NTOK,3D] bf16
    __bf16* gb   = (__bf16*)ws; ws += (size_t)NTOK * D4 * 2;       // [NTOK,4D] bf16 (alias)
    __bf16* hb   = (__bf16*)ws; ws += (size_t)NTOK * D  * 2;       // ln out
    __bf16* yb   = (__bf16*)ws; ws += (size_t)NTOK * D  * 2;       // attn out
    __bf16* awt  = (__bf16*)ws; ws += (size_t)L * D3 * D   * 2;    // attn_w^T (all layers)
    __bf16* pwt  = (__bf16*)ws; ws += (size_t)L * D  * D   * 2;    // proj_w^T
    __bf16* fwt  = (__bf16*)ws; ws += (size_t)L * D4 * D   * 2;    // fc_w^T
    __bf16* fpwt = (__bf16*)ws; ws += (size_t)L * D  * D4  * 2;    // fcp_w^T
    __bf16* xf   = (__bf16*)ws; ws += (size_t)B * D    * 2;

    // embed + all 16 weight transposes in one dispatch
    prep_kernel<<<3072 + 6912 * L, 256, 0, stream>>>(idx, wte, wpe, x,
                                                     attn_w, proj_w, fc_w, fcp_w,
                                                     awt, pwt, fwt, fpwt);

    for (int l = 0; l < L; ++l) {
        const float* l1w = ln1_w + l * D;
        const float* l1b = ln1_b + l * D;
        const float* ab  = attn_b + l * D3;
        const float* pb  = proj_b + l * D;
        const float* l2w = ln2_w + l * D;
        const float* l2b = ln2_b + l * D;
        const float* fb  = fc_b + l * D4;
        const float* fpb = fcp_b + l * D;
        const __bf16* awl  = awt  + (size_t)l * D3 * D;
        const __bf16* pwl  = pwt  + (size_t)l * D  * D;
        const __bf16* fwl  = fwt  + (size_t)l * D4 * D;
        const __bf16* fpwl = fpwt + (size_t)l * D  * D4;

        // h = ln1(x)
        ln_kernel<<<NTOK, 256, 0, stream>>>(x, l1w, l1b, hb, 1, 0);
        // qkv = h @ aw + ab  [bf16]  (128x64 tiles: 36x32 = 1152 blocks)
        gemm_bt<false><<<dim3(D3 / 64, NTOK / 128), 256, 0, stream>>>(
            hb, awl, ab, qkvb, D3, D);
        // y = flash-attention(qkv)  [bf16]  (64-row q-tiles: 768 blocks)
        attn_mfma<<<B * H * (T / 64), 256, 0, stream>>>(qkvb, yb);
        // x = x + y @ pw + pb   (64x64 tiles: 768 blocks = 3/CU)
        gemm64<<<dim3(D / 64, NTOK / 64), 256, 0, stream>>>(
            yb, pwl, pb, x, x, D, D);
        // h = ln2(x)
        ln_kernel<<<NTOK, 256, 0, stream>>>(x, l2w, l2b, hb, 1, 0);
        // gb = gelu(h @ fw + fb)  [bf16]  (128x64 tiles: 48x32 = 1536 blocks = 6/CU)
        gemm_bt<true><<<dim3(D4 / 64, NTOK / 128), 256, 0, stream>>>(
            hb, fwl, fb, gb, D4, D);
        // x = x + gb @ fpw + fpb  (64x64 tiles)
        gemm64<<<dim3(D / 64, NTOK / 64), 256, 0, stream>>>(
            gb, fpwl, fpb, x, x, D, D4);
    }

    ln_kernel<<<B, 256, 0, stream>>>(x, lnf_w, lnf_b, xf, T, T - 1);
    logits_kernel<<<(V + 3) / 4, 256, 0, stream>>>(xf, wte, out);
}

// Round 7
// 1280.242 us; speedup vs baseline: 1.0402x; 1.0402x over previous
//
#include <hip/hip_runtime.h>
#include <math.h>

#define V 50257
#define B 2
#define T 2048
#define D 768
#define H 12
#define HD 64
#define L 4
#define D3 (3*D)
#define D4 (4*D)
#define NTOK (B*T)          // 4096
#define EPS 1e-5f

typedef __bf16 v8bf __attribute__((ext_vector_type(8)));
typedef __bf16 v4bf __attribute__((ext_vector_type(4)));
typedef unsigned short v8us __attribute__((ext_vector_type(8)));
typedef float  v4f  __attribute__((ext_vector_type(4)));

#define GAS(p) ((const __attribute__((address_space(1))) void*)(p))
#define LAS(p) ((__attribute__((address_space(3))) void*)(p))

// swizzled LDS tile addressing: 64-elem (128B) rows, 16B chunks, chunk ^= row&7.
#define LIDX(row, chunk) ((row)*64 + ((((chunk) ^ ((row)&7)))<<3))
// 256-elem (512B) rows for the 256-wide C-tile repack
#define C2IDX(row, chunk) ((row)*256 + ((((chunk) ^ (((row)&7)<<2)))<<3))

#define SBAR() asm volatile("s_barrier" ::: "memory")

// fast erf (Abramowitz-Stegun 7.1.26, max abs err 1.5e-7) for GELU
__device__ __forceinline__ float gelu_fast(float x) {
    float z  = fabsf(x) * 0.70710678118f;
    float tt = 1.f / (1.f + 0.3275911f * z);
    float poly = tt * (0.254829592f + tt * (-0.284496736f + tt * (1.421413741f +
                 tt * (-1.453152027f + tt * 1.061405429f))));
    float er = 1.f - poly * __expf(-z * z);
    er = (x < 0.f) ? -er : er;
    return 0.5f * x * (1.f + er);
}

// ------- prep: embed (vectorized) + ALL-layer weight convert+transpose ------
__global__ __launch_bounds__(256) void prep_kernel(
        const int* __restrict__ idx, const float* __restrict__ wte,
        const float* __restrict__ wpe, float* __restrict__ x,
        const float* __restrict__ aw_all,  const float* __restrict__ pw_all,
        const float* __restrict__ fw_all,  const float* __restrict__ fpw_all,
        __bf16* __restrict__ awt_all, __bf16* __restrict__ pwt_all,
        __bf16* __restrict__ fwt_all, __bf16* __restrict__ fpwt_all) {
    int bid = blockIdx.x;
    if (bid < 3072) {
        int e = (bid * 256 + threadIdx.x) * 4;      // 3072*256*4 = NTOK*D exactly
        int pos = e / D;
        int d   = e - pos * D;
        int t   = pos & (T - 1);
        int tok = idx[pos];
        const float4 a  = *(const float4*)(wte + (size_t)tok * D + d);
        const float4 p4 = *(const float4*)(wpe + (size_t)t * D + d);
        float4 r; r.x = a.x + p4.x; r.y = a.y + p4.y; r.z = a.z + p4.z; r.w = a.w + p4.w;
        *(float4*)(x + e) = r;
        return;
    }
    bid -= 3072;
    const int l = bid / 6912; bid -= l * 6912;
    const float* W; __bf16* Wt; int K, N, bx, by;
    if (bid < 1728)      {             W = aw_all  + (size_t)l * D  * D3; Wt = awt_all  + (size_t)l * D3 * D;  K = D;  N = D3; bx = bid % 72; by = bid / 72; }
    else if (bid < 2304) { bid -= 1728; W = pw_all  + (size_t)l * D  * D;  Wt = pwt_all  + (size_t)l * D  * D;  K = D;  N = D;  bx = bid % 24; by = bid / 24; }
    else if (bid < 4608) { bid -= 2304; W = fw_all  + (size_t)l * D  * D4; Wt = fwt_all  + (size_t)l * D4 * D;  K = D;  N = D4; bx = bid % 96; by = bid / 96; }
    else                 { bid -= 4608; W = fpw_all + (size_t)l * D4 * D;  Wt = fpwt_all + (size_t)l * D  * D4; K = D4; N = D;  bx = bid % 24; by = bid / 24; }
    __shared__ float t[32][33];
    const int n0 = bx * 32, k0 = by * 32;
    const int tx = threadIdx.x & 31, ty = threadIdx.x >> 5;
    #pragma unroll
    for (int p = 0; p < 4; ++p)
        t[ty + 8 * p][tx] = W[(size_t)(k0 + ty + 8 * p) * N + n0 + tx];
    __syncthreads();
    #pragma unroll
    for (int p = 0; p < 4; ++p)
        Wt[(size_t)(n0 + ty + 8 * p) * K + k0 + tx] = (__bf16)t[tx][ty + 8 * p];
}

// ---------------- layernorm: fp32 in, bf16 out ----------------
__global__ __launch_bounds__(256) void ln_kernel(const float* __restrict__ X,
                                                 const float* __restrict__ w,
                                                 const float* __restrict__ b,
                                                 __bf16* __restrict__ Y,
                                                 int src_mul, int src_off) {
    int srow = blockIdx.x * src_mul + src_off;
    const float* xr = X + (size_t)srow * D;
    float v[3];
    float s = 0.f, s2 = 0.f;
    #pragma unroll
    for (int j = 0; j < 3; ++j) {
        v[j] = xr[threadIdx.x + 256 * j];
        s += v[j];
        s2 += v[j] * v[j];
    }
    #pragma unroll
    for (int off = 32; off; off >>= 1) {
        s  += __shfl_xor(s, off);
        s2 += __shfl_xor(s2, off);
    }
    __shared__ float ss[4], ss2[4];
    int wave = threadIdx.x >> 6, lane = threadIdx.x & 63;
    if (lane == 0) { ss[wave] = s; ss2[wave] = s2; }
    __syncthreads();
    s  = ss[0] + ss[1] + ss[2] + ss[3];
    s2 = ss2[0] + ss2[1] + ss2[2] + ss2[3];
    float mu  = s * (1.f / D);
    float var = s2 * (1.f / D) - mu * mu;
    float rs  = rsqrtf(var + EPS);
    __bf16* yr = Y + (size_t)blockIdx.x * D;
    #pragma unroll
    for (int j = 0; j < 3; ++j) {
        int c = threadIdx.x + 256 * j;
        yr[c] = (__bf16)((v[j] - mu) * rs * w[c] + b[c]);
    }
}

// ---- bf16 MFMA GEMM 256x256-tile, 512 threads / 8 waves, BK=32, dbuf -------
// Each wave owns a 128x64 accumulator: 32 MFMAs from 12 ds_read_b128
// (2.67 MFMA/read vs 2.0 at 64x64) -> per-CU step is MFMA-dominant.
// Fragment-major LDS: group g holds exactly one wave-fragment, lane-contiguous
// (conflict-free by construction; staged by per-lane global src + linear dst).
template<bool DOGELU>
__global__ __launch_bounds__(512) void gemm256(const __bf16* __restrict__ A,
                                               const __bf16* __restrict__ Wt,
                                               const float* __restrict__ bias,
                                               __bf16* __restrict__ Cout,
                                               int N, int K) {
    // buffer b: A frags at b*16384, B frags at b*16384 + 8192  (64 KB total)
    __shared__ __align__(16) __bf16 sm[32768];
    const int tid  = threadIdx.x;
    const int w    = tid >> 6;          // 0..7
    const int lane = tid & 63;
    const int wm   = w >> 2;            // 0..1: row half
    const int wn   = w & 3;             // 0..3: col quarter

    // XCD-chunked work remap (nwg % 8 == 0: fc 192, qkv 144)
    int fid = blockIdx.y * gridDim.x + blockIdx.x;
    const int nwg = gridDim.x * gridDim.y;
    fid = (fid & 7) * (nwg >> 3) + (fid >> 3);
    const int row0 = (fid / gridDim.x) * 256;
    const int col0 = (fid % gridDim.x) * 256;

    // staging: 16 A-groups (wm 2 x i 8), 16 B-groups (wn 4 x j 4); 2+2 per wave.
    // group g semantics: lane holds elem [16 rows of g][k0 + (lane>>4)*8 ..+8]
    const int l15 = lane & 15;
    const int lq8 = (lane >> 4) * 8;
    const __bf16* gAsrc[2];
    const __bf16* gBsrc[2];
    {
        #pragma unroll
        for (int rep = 0; rep < 2; ++rep) {
            int ga = w * 2 + rep;                   // 0..15
            int awm = ga >> 3, ai = ga & 7;
            gAsrc[rep] = A + (size_t)(row0 + awm * 128 + ai * 16 + l15) * K + lq8;
            int gb = w * 2 + rep;
            int bwn = gb >> 2, bj = gb & 3;
            gBsrc[rep] = Wt + (size_t)(col0 + bwn * 64 + bj * 16 + l15) * K + lq8;
        }
    }

    auto stage = [&](int bsel) {
        __bf16* dst = sm + bsel * 16384;
        #pragma unroll
        for (int rep = 0; rep < 2; ++rep) {
            const int g = w * 2 + rep;
            __builtin_amdgcn_global_load_lds(GAS(gAsrc[rep]), LAS(dst + (size_t)(g * 64 + lane) * 8), 16, 0, 0);
            __builtin_amdgcn_global_load_lds(GAS(gBsrc[rep]), LAS(dst + 8192 + (size_t)(g * 64 + lane) * 8), 16, 0, 0);
            gAsrc[rep] += 32; gBsrc[rep] += 32;
        }
    };

    const int nt = K >> 5;              // 24 for K=768
    stage(0);                           // 4 loads in flight

    v4f acc[8][4] = {};
    for (int t = 0; t < nt; ++t) {
        const int cb = (t & 1) * 16384;
        if (t + 1 < nt) {
            stage((t + 1) & 1);         // 8 in flight
            asm volatile("s_waitcnt vmcnt(4)\n\ts_barrier" ::: "memory");
        } else {
            asm volatile("s_waitcnt vmcnt(0)\n\ts_barrier" ::: "memory");
        }
        v8bf bf[4];
        #pragma unroll
        for (int j = 0; j < 4; ++j)
            bf[j] = *(const v8bf*)(sm + cb + 8192 + (size_t)((wn * 4 + j) * 64 + lane) * 8);
        #pragma unroll
        for (int i = 0; i < 8; ++i) {
            v8bf af = *(const v8bf*)(sm + cb + (size_t)((wm * 8 + i) * 64 + lane) * 8);
            #pragma unroll
            for (int j = 0; j < 4; ++j)
                acc[i][j] = __builtin_amdgcn_mfma_f32_16x16x32_bf16(af, bf[j], acc[i][j], 0, 0, 0);
        }
        SBAR();                         // all waves done reading buf (t&1)
    }

    // ---- epilogue: two 128-row halves through LDS -> full-line stores ------
    const int er = (lane >> 4) * 4;
    const int ec = lane & 15;
    #pragma unroll
    for (int half = 0; half < 2; ++half) {
        if (wm == half) {
            #pragma unroll
            for (int j = 0; j < 4; ++j) {
                const int col = wn * 64 + j * 16 + ec;
                const float bval = bias[col0 + col];
                const int chunk = col >> 3, ce = col & 7;
                #pragma unroll
                for (int i = 0; i < 8; ++i) {
                    const int rowb = i * 16 + er;
                    #pragma unroll
                    for (int rr = 0; rr < 4; ++rr) {
                        float vv = acc[i][j][rr] + bval;
                        if (DOGELU) vv = gelu_fast(vv);
                        sm[C2IDX(rowb + rr, chunk) + ce] = (__bf16)vv;
                    }
                }
            }
        }
        __syncthreads();
        #pragma unroll
        for (int c = 0; c < 8; ++c) {
            const int chunkid = tid + c * 512;      // 0..4095
            const int row = chunkid >> 5;           // 0..127
            const int cc  = chunkid & 31;
            *(v8us*)(void*)(Cout + (size_t)(row0 + half * 128 + row) * N + col0 + cc * 8) =
                *(const v8us*)(const void*)(sm + C2IDX(row, cc));
        }
        __syncthreads();
    }
}

// ---- bf16 MFMA GEMM 64x64, BK=64, 3-deep ring + counted vmcnt (fp32+res) ---
__global__ __launch_bounds__(256) void gemm64(const __bf16* __restrict__ A,
                                              const __bf16* __restrict__ Wt,
                                              const float* __restrict__ bias,
                                              const float* __restrict__ res,
                                              float* __restrict__ Cout,
                                              int N, int K) {
    __shared__ __align__(16) __bf16 sm[24576];   // 3 x (A 4096 | B 4096) = 48 KB
    const int tid  = threadIdx.x;
    const int w    = tid >> 6;
    const int lane = tid & 63;

    int fid = blockIdx.y * gridDim.x + blockIdx.x;
    const int nwg = gridDim.x * gridDim.y;
    fid = (fid & 7) * (nwg >> 3) + (fid >> 3);
    const int row0 = (fid / gridDim.x) * 64;
    const int col0 = (fid % gridDim.x) * 64;

    const int srow = ((tid >> 7) & 3) * 16 + (tid & 15);
    const int sk   = ((tid >> 4) & 7) * 8;
    const __bf16* gA0 = A  + (size_t)(row0 + srow) * K + sk;
    const __bf16* gA1 = gA0 + (size_t)32 * K;
    const __bf16* gB0 = Wt + (size_t)(col0 + srow) * K + sk;
    const __bf16* gB1 = gB0 + (size_t)32 * K;

    auto stage = [&](int bsel) {
        __bf16* dst = sm + bsel * 8192;
        __builtin_amdgcn_global_load_lds(GAS(gA0), LAS(dst + (size_t)tid * 8), 16, 0, 0);
        __builtin_amdgcn_global_load_lds(GAS(gA1), LAS(dst + (size_t)(tid + 256) * 8), 16, 0, 0);
        __builtin_amdgcn_global_load_lds(GAS(gB0), LAS(dst + 4096 + (size_t)tid * 8), 16, 0, 0);
        __builtin_amdgcn_global_load_lds(GAS(gB1), LAS(dst + 4096 + (size_t)(tid + 256) * 8), 16, 0, 0);
        gA0 += 64; gA1 += 64; gB0 += 64; gB1 += 64;
    };

    const int wr = w >> 1, wc = w & 1;
    const __bf16* rA = sm + wr * 2048 + lane * 8;
    const __bf16* rB = sm + 4096 + wc * 2048 + lane * 8;

    const int nt = K >> 6;          // 12 (proj) / 48 (fcp)
    stage(0); stage(1);

    v4f acc[2][2] = {};
    for (int t = 0; t < nt; ++t) {
        const int cb = (t % 3) * 8192;
        if (t + 2 < nt) {
            stage((t + 2) % 3);
            asm volatile("s_waitcnt vmcnt(8)\n\ts_barrier" ::: "memory");
        } else if (t + 1 < nt) {
            asm volatile("s_waitcnt vmcnt(4)\n\ts_barrier" ::: "memory");
        } else {
            asm volatile("s_waitcnt vmcnt(0)\n\ts_barrier" ::: "memory");
        }
        #pragma unroll
        for (int h = 0; h < 2; ++h) {
            v8bf af[2], bfr[2];
            #pragma unroll
            for (int i = 0; i < 2; ++i) af[i]  = *(const v8bf*)(rA + cb + i * 1024 + h * 512);
            #pragma unroll
            for (int j = 0; j < 2; ++j) bfr[j] = *(const v8bf*)(rB + cb + j * 1024 + h * 512);
            #pragma unroll
            for (int i = 0; i < 2; ++i)
                #pragma unroll
                for (int j = 0; j < 2; ++j)
                    acc[i][j] = __builtin_amdgcn_mfma_f32_16x16x32_bf16(af[i], bfr[j], acc[i][j], 0, 0, 0);
        }
        SBAR();
    }

    // ---- epilogue: acc+bias -> LDS fp32 (swizzled) -> coalesced res+store ----
    float* smf = (float*)sm;        // 64x64 fp32 = 16 KB
    const int er = (lane >> 4) * 4;
    const int ec = lane & 15;
    #pragma unroll
    for (int j = 0; j < 2; ++j) {
        const int col = wc * 32 + j * 16 + ec;
        const float bval = bias[col0 + col];
        #pragma unroll
        for (int i = 0; i < 2; ++i) {
            #pragma unroll
            for (int rr = 0; rr < 4; ++rr) {
                const int row = wr * 32 + i * 16 + er + rr;
                smf[row * 64 + (col ^ ((row & 3) << 4))] = acc[i][j][rr] + bval;
            }
        }
    }
    __syncthreads();
    #pragma unroll
    for (int c = 0; c < 4; ++c) {
        const int chunkid = tid + c * 256;         // 0..1023
        const int row = chunkid >> 4;
        const int c0  = (chunkid & 15) * 4;
        float4 vv = *(const float4*)(smf + row * 64 + (c0 ^ ((row & 3) << 4)));
        const float4 rv = *(const float4*)(res + (size_t)(row0 + row) * N + col0 + c0);
        vv.x += rv.x; vv.y += rv.y; vv.z += rv.z; vv.w += rv.w;
        *(float4*)(Cout + (size_t)(row0 + row) * N + col0 + c0) = vv;
    }
}

// ---------------- MFMA flash attention: 64 q-rows/block, swapped QK^T -------
__global__ __launch_bounds__(256) void attn_mfma(const __bf16* __restrict__ qkv,
                                                 __bf16* __restrict__ y) {
    __shared__ __align__(16) __bf16 Qs[4096];
    __shared__ __align__(16) __bf16 Ks[4096];
    __shared__ __align__(16) __bf16 Vt[4096];
    __shared__ __align__(16) __bf16 Ps[4][1024];

    const int tid  = threadIdx.x;
    const int w    = tid >> 6;
    const int lane = tid & 63;
    const int quad = lane >> 4;
    const int l4   = lane & 15;

    // XCD-chunked remap
    int fid = blockIdx.x;
    const int nwg = gridDim.x;
    fid = (fid & 7) * (nwg >> 3) + (fid >> 3);

    const int qt = 31 - (fid & 31);              // big tiles first
    const int bh = fid >> 5;
    const int b  = bh / H;
    const int h  = bh - b * H;
    const int q0 = qt * 64;

    const __bf16* base = qkv + (size_t)(b * T) * D3 + h * HD;

    // stage Q tile (64 rows), swizzled
    {
        int c = tid;
        #pragma unroll
        for (int rep = 0; rep < 2; ++rep, c += 256) {
            int row = c >> 3, ch = c & 7;
            v8us v = *(const v8us*)(const void*)(base + (size_t)(q0 + row) * D3 + ch * 8);
            *(v8us*)(void*)(Qs + LIDX(row, ch)) = v;
        }
    }

    const int krow = tid >> 3, kch = tid & 7;
    const int vkp = tid & 31, vdc = tid >> 5;
    const __bf16* kp0 = base + D     + (size_t)krow * D3 + kch * 8;
    const __bf16* kp1 = kp0 + (size_t)32 * D3;
    const __bf16* vp0 = base + 2 * D + (size_t)(2 * vkp) * D3 + vdc * 8;
    const __bf16* vp1 = vp0 + D3;

    v8us kr0 = *(const v8us*)(const void*)kp0;
    v8us kr1 = *(const v8us*)(const void*)kp1;
    v8us vr0 = *(const v8us*)(const void*)vp0;
    v8us vr1 = *(const v8us*)(const void*)vp1;

    float m_local = -INFINITY;      // running max for q = q0 + w*16 + l4
    v4f o[4] = {};
    v4f sacc = {};                  // softmax denominators via ones-MFMA
    v8bf qf[2];
    v8bf vones;
    #pragma unroll
    for (int i = 0; i < 8; ++i) vones[i] = (__bf16)1.0f;

    const int nt = qt + 1;
    const size_t adv = (size_t)64 * D3;
    const int qrow = q0 + w * 16 + l4;

    for (int kt = 0; kt < nt; ++kt) {
        const int k0 = kt * 64;
        // ---- write prefetched K tile (natural rows, swizzled) ----
        *(v8us*)(void*)(Ks + LIDX(krow, kch))      = kr0;
        *(v8us*)(void*)(Ks + LIDX(krow + 32, kch)) = kr1;
        // ---- write prefetched V transposed: Vt[dim][key], swizzled ----
        #pragma unroll
        for (int j = 0; j < 8; ++j) {
            int dim = vdc * 8 + j;
            int idx = dim * 64 + ((((vkp >> 2) ^ (dim & 7))) << 3) + ((vkp & 3) << 1);
            *(unsigned int*)(void*)(Vt + idx) =
                ((unsigned int)vr1[j] << 16) | (unsigned int)vr0[j];
        }
        __syncthreads();

        if (kt == 0) {
            #pragma unroll
            for (int kh = 0; kh < 2; ++kh)
                qf[kh] = *(const v8bf*)(Qs + LIDX(w * 16 + l4, kh * 4 + quad));
        }
        // ---- issue next tile's global loads (latency hidden by compute) ----
        if (kt + 1 < nt) {
            kp0 += adv; kp1 += adv; vp0 += adv; vp1 += adv;
            kr0 = *(const v8us*)(const void*)kp0;
            kr1 = *(const v8us*)(const void*)kp1;
            vr0 = *(const v8us*)(const void*)vp0;
            vr1 = *(const v8us*)(const void*)vp1;
        }

        // ---- S^T = K Q^T : lane holds keys (jb*16 + quad*4 + rg) for q=l4 ----
        v4f s[4] = {};
        __builtin_amdgcn_s_setprio(1);
        #pragma unroll
        for (int kh = 0; kh < 2; ++kh) {
            #pragma unroll
            for (int jb = 0; jb < 4; ++jb) {
                v8bf bk = *(const v8bf*)(Ks + LIDX(jb * 16 + l4, kh * 4 + quad));
                s[jb] = __builtin_amdgcn_mfma_f32_16x16x32_bf16(bk, qf[kh], s[jb], 0, 0, 0);
            }
        }
        __builtin_amdgcn_s_setprio(0);

        // ---- online softmax, lane-local row ----
        float sv[4][4];
        float mx = -INFINITY;
        #pragma unroll
        for (int jb = 0; jb < 4; ++jb) {
            #pragma unroll
            for (int rg = 0; rg < 4; ++rg) {
                float vvv = s[jb][rg] * 0.125f;
                if (k0 + jb * 16 + quad * 4 + rg > qrow) vvv = -INFINITY;
                sv[jb][rg] = vvv;
                mx = fmaxf(mx, vvv);
            }
        }
        mx = fmaxf(mx, __shfl_xor(mx, 16));
        mx = fmaxf(mx, __shfl_xor(mx, 32));
        // defer-max: rescale only when some lane's max grew past m_local + 8
        if (!__all(mx <= m_local + 8.f)) {
            const float mnew    = fmaxf(m_local, mx);
            const float alpha_l = __expf(m_local - mnew);
            m_local = mnew;
            float a4[4];
            #pragma unroll
            for (int r = 0; r < 4; ++r) a4[r] = __shfl(alpha_l, quad * 4 + r);
            #pragma unroll
            for (int r = 0; r < 4; ++r) {
                sacc[r] *= a4[r];
                #pragma unroll
                for (int db = 0; db < 4; ++db) o[db][r] *= a4[r];
            }
        }
        // ---- P -> per-wave LDS (packed b64 stores, swizzled) ----
        #pragma unroll
        for (int jb = 0; jb < 4; ++jb) {
            v4bf pk;
            #pragma unroll
            for (int rg = 0; rg < 4; ++rg)
                pk[rg] = (__bf16)__expf(sv[jb][rg] - m_local);
            *(v4bf*)(void*)(&Ps[w][LIDX(l4, jb * 2 + (quad >> 1)) + ((quad & 1) << 2)]) = pk;
        }
        // ---- O += P V ; denom += P 1 ----
        __builtin_amdgcn_s_setprio(1);
        #pragma unroll
        for (int kh = 0; kh < 2; ++kh) {
            v8bf ap = *(const v8bf*)(&Ps[w][LIDX(l4, kh * 4 + quad)]);
            sacc = __builtin_amdgcn_mfma_f32_16x16x32_bf16(ap, vones, sacc, 0, 0, 0);
            #pragma unroll
            for (int db = 0; db < 4; ++db) {
                v8bf bv = *(const v8bf*)(Vt + LIDX(db * 16 + l4, kh * 4 + quad));
                o[db] = __builtin_amdgcn_mfma_f32_16x16x32_bf16(ap, bv, o[db], 0, 0, 0);
            }
        }
        __builtin_amdgcn_s_setprio(0);
        __syncthreads();
    }

    // ---- epilogue ----
    #pragma unroll
    for (int db = 0; db < 4; ++db) {
        #pragma unroll
        for (int r = 0; r < 4; ++r) {
            const int q = q0 + w * 16 + quad * 4 + r;
            y[(size_t)(b * T + q) * D + h * HD + db * 16 + l4] =
                (__bf16)(o[db][r] / sacc[r]);
        }
    }
}

// ---------------- lm head: both batch rows per wte pass ---------------------
__global__ __launch_bounds__(256) void logits_kernel(const __bf16* __restrict__ xf,
                                                     const float* __restrict__ wte,
                                                     float* __restrict__ out) {
    int wave = threadIdx.x >> 6;
    int lane = threadIdx.x & 63;
    int v = blockIdx.x * 4 + wave;
    if (v >= V) return;
    const float4* wr = (const float4*)(wte + (size_t)v * D);   // 192 chunks
    const v4bf*   x0 = (const v4bf*)(xf);
    const v4bf*   x1 = (const v4bf*)(xf + D);
    float s0 = 0.f, s1 = 0.f;
    #pragma unroll
    for (int j = 0; j < 3; ++j) {
        float4 wv = wr[lane + 64 * j];
        v4bf a0 = x0[lane + 64 * j];
        v4bf a1 = x1[lane + 64 * j];
        s0 = fmaf(wv.x, (float)a0[0], s0); s0 = fmaf(wv.y, (float)a0[1], s0);
        s0 = fmaf(wv.z, (float)a0[2], s0); s0 = fmaf(wv.w, (float)a0[3], s0);
        s1 = fmaf(wv.x, (float)a1[0], s1); s1 = fmaf(wv.y, (float)a1[1], s1);
        s1 = fmaf(wv.z, (float)a1[2], s1); s1 = fmaf(wv.w, (float)a1[3], s1);
    }
    #pragma unroll
    for (int off = 32; off; off >>= 1) {
        s0 += __shfl_xor(s0, off);
        s1 += __shfl_xor(s1, off);
    }
    if (lane == 0) { out[v] = s0; out[V + v] = s1; }
}

extern "C" void kernel_launch(void* const* d_in, const int* in_sizes, int n_in,
                              void* d_out, int out_size, void* d_ws, size_t ws_size,
                              hipStream_t stream) {
    const int*   idx    = (const int*)  d_in[0];
    const float* wte    = (const float*)d_in[1];
    const float* wpe    = (const float*)d_in[2];
    const float* ln1_w  = (const float*)d_in[3];
    const float* ln1_b  = (const float*)d_in[4];
    const float* attn_w = (const float*)d_in[5];
    const float* attn_b = (const float*)d_in[6];
    const float* proj_w = (const float*)d_in[7];
    const float* proj_b = (const float*)d_in[8];
    const float* ln2_w  = (const float*)d_in[9];
    const float* ln2_b  = (const float*)d_in[10];
    const float* fc_w   = (const float*)d_in[11];
    const float* fc_b   = (const float*)d_in[12];
    const float* fcp_w  = (const float*)d_in[13];
    const float* fcp_b  = (const float*)d_in[14];
    const float* lnf_w  = (const float*)d_in[15];
    const float* lnf_b  = (const float*)d_in[16];
    float* out = (float*)d_out;

    char* ws = (char*)d_ws;
    float*  x    = (float*)ws;  ws += (size_t)NTOK * D  * 4;       // residual stream fp32
    __bf16* qkvb = (__bf16*)ws;                                     // [NTOK,3D] bf16
    __bf16* gb   = (__bf16*)ws; ws += (size_t)NTOK * D4 * 2;       // [NTOK,4D] bf16 (alias)
    __bf16* hb   = (__bf16*)ws; ws += (size_t)NTOK * D  * 2;       // ln out
    __bf16* yb   = (__bf16*)ws; ws += (size_t)NTOK * D  * 2;       // attn out
    __bf16* awt  = (__bf16*)ws; ws += (size_t)L * D3 * D   * 2;    // attn_w^T (all layers)
    __bf16* pwt  = (__bf16*)ws; ws += (size_t)L * D  * D   * 2;    // proj_w^T
    __bf16* fwt  = (__bf16*)ws; ws += (size_t)L * D4 * D   * 2;    // fc_w^T
    __bf16* fpwt = (__bf16*)ws; ws += (size_t)L * D  * D4  * 2;    // fcp_w^T
    __bf16* xf   = (__bf16*)ws; ws += (size_t)B * D    * 2;

    // embed + all 16 weight transposes in one dispatch
    prep_kernel<<<3072 + 6912 * L, 256, 0, stream>>>(idx, wte, wpe, x,
                                                     attn_w, proj_w, fc_w, fcp_w,
                                                     awt, pwt, fwt, fpwt);

    for (int l = 0; l < L; ++l) {
        const float* l1w = ln1_w + l * D;
        const float* l1b = ln1_b + l * D;
        const float* ab  = attn_b + l * D3;
        const float* pb  = proj_b + l * D;
        const float* l2w = ln2_w + l * D;
        const float* l2b = ln2_b + l * D;
        const float* fb  = fc_b + l * D4;
        const float* fpb = fcp_b + l * D;
        const __bf16* awl  = awt  + (size_t)l * D3 * D;
        const __bf16* pwl  = pwt  + (size_t)l * D  * D;
        const __bf16* fwl  = fwt  + (size_t)l * D4 * D;
        const __bf16* fpwl = fpwt + (size_t)l * D  * D4;

        // h = ln1(x)
        ln_kernel<<<NTOK, 256, 0, stream>>>(x, l1w, l1b, hb, 1, 0);
        // qkv = h @ aw + ab  [bf16]  (256x256 tiles: 9x16 = 144 blocks)
        gemm256<false><<<dim3(D3 / 256, NTOK / 256), 512, 0, stream>>>(
            hb, awl, ab, qkvb, D3, D);
        // y = flash-attention(qkv)  [bf16]  (64-row q-tiles: 768 blocks)
        attn_mfma<<<B * H * (T / 64), 256, 0, stream>>>(qkvb, yb);
        // x = x + y @ pw + pb   (64x64 tiles: 768 blocks = 3/CU)
        gemm64<<<dim3(D / 64, NTOK / 64), 256, 0, stream>>>(
            yb, pwl, pb, x, x, D, D);
        // h = ln2(x)
        ln_kernel<<<NTOK, 256, 0, stream>>>(x, l2w, l2b, hb, 1, 0);
        // gb = gelu(h @ fw + fb)  [bf16]  (256x256 tiles: 12x16 = 192 blocks)
        gemm256<true><<<dim3(D4 / 256, NTOK / 256), 512, 0, stream>>>(
            hb, fwl, fb, gb, D4, D);
        // x = x + gb @ fpw + fpb  (64x64 tiles)
        gemm64<<<dim3(D / 64, NTOK / 64), 256, 0, stream>>>(
            gb, fpwl, fpb, x, x, D, D4);
    }

    ln_kernel<<<B, 256, 0, stream>>>(x, lnf_w, lnf_b, xf, T, T - 1);
    logits_kernel<<<(V + 3) / 4, 256, 0, stream>>>(xf, wte, out);
}

// Round 8
// 1251.187 us; speedup vs baseline: 1.0644x; 1.0232x over previous
//
#include <hip/hip_runtime.h>
#include <math.h>

#define V 50257
#define B 2
#define T 2048
#define D 768
#define H 12
#define HD 64
#define L 4
#define D3 (3*D)
#define D4 (4*D)
#define NTOK (B*T)          // 4096
#define EPS 1e-5f

typedef __bf16 v8bf __attribute__((ext_vector_type(8)));
typedef __bf16 v4bf __attribute__((ext_vector_type(4)));
typedef unsigned short v8us __attribute__((ext_vector_type(8)));
typedef float  v4f  __attribute__((ext_vector_type(4)));

#define GAS(p) ((const __attribute__((address_space(1))) void*)(p))
#define LAS(p) ((__attribute__((address_space(3))) void*)(p))

// swizzled LDS tile addressing: 64-elem (128B) rows, 16B chunks, chunk ^= row&7.
#define LIDX(row, chunk) ((row)*64 + ((((chunk) ^ ((row)&7)))<<3))
// same for 128-elem (256B) rows (C-tile repack)
#define CIDX(row, chunk) ((row)*128 + ((((chunk) ^ ((row)&7)))<<3))

#define SBAR() asm volatile("s_barrier" ::: "memory")

// fast erf (Abramowitz-Stegun 7.1.26, max abs err 1.5e-7) for GELU
__device__ __forceinline__ float gelu_fast(float x) {
    float z  = fabsf(x) * 0.70710678118f;
    float tt = 1.f / (1.f + 0.3275911f * z);
    float poly = tt * (0.254829592f + tt * (-0.284496736f + tt * (1.421413741f +
                 tt * (-1.453152027f + tt * 1.061405429f))));
    float er = 1.f - poly * __expf(-z * z);
    er = (x < 0.f) ? -er : er;
    return 0.5f * x * (1.f + er);
}

// ------- prep: embed (vectorized) + ALL-layer weight convert+transpose ------
__global__ __launch_bounds__(256) void prep_kernel(
        const int* __restrict__ idx, const float* __restrict__ wte,
        const float* __restrict__ wpe, float* __restrict__ x,
        const float* __restrict__ aw_all,  const float* __restrict__ pw_all,
        const float* __restrict__ fw_all,  const float* __restrict__ fpw_all,
        __bf16* __restrict__ awt_all, __bf16* __restrict__ pwt_all,
        __bf16* __restrict__ fwt_all, __bf16* __restrict__ fpwt_all) {
    int bid = blockIdx.x;
    if (bid < 3072) {
        int e = (bid * 256 + threadIdx.x) * 4;      // 3072*256*4 = NTOK*D exactly
        int pos = e / D;
        int d   = e - pos * D;
        int t   = pos & (T - 1);
        int tok = idx[pos];
        const float4 a  = *(const float4*)(wte + (size_t)tok * D + d);
        const float4 p4 = *(const float4*)(wpe + (size_t)t * D + d);
        float4 r; r.x = a.x + p4.x; r.y = a.y + p4.y; r.z = a.z + p4.z; r.w = a.w + p4.w;
        *(float4*)(x + e) = r;
        return;
    }
    bid -= 3072;
    const int l = bid / 6912; bid -= l * 6912;
    const float* W; __bf16* Wt; int K, N, bx, by;
    if (bid < 1728)      {             W = aw_all  + (size_t)l * D  * D3; Wt = awt_all  + (size_t)l * D3 * D;  K = D;  N = D3; bx = bid % 72; by = bid / 72; }
    else if (bid < 2304) { bid -= 1728; W = pw_all  + (size_t)l * D  * D;  Wt = pwt_all  + (size_t)l * D  * D;  K = D;  N = D;  bx = bid % 24; by = bid / 24; }
    else if (bid < 4608) { bid -= 2304; W = fw_all  + (size_t)l * D  * D4; Wt = fwt_all  + (size_t)l * D4 * D;  K = D;  N = D4; bx = bid % 96; by = bid / 96; }
    else                 { bid -= 4608; W = fpw_all + (size_t)l * D4 * D;  Wt = fpwt_all + (size_t)l * D  * D4; K = D4; N = D;  bx = bid % 24; by = bid / 24; }
    __shared__ float t[32][33];
    const int n0 = bx * 32, k0 = by * 32;
    const int tx = threadIdx.x & 31, ty = threadIdx.x >> 5;
    #pragma unroll
    for (int p = 0; p < 4; ++p)
        t[ty + 8 * p][tx] = W[(size_t)(k0 + ty + 8 * p) * N + n0 + tx];
    __syncthreads();
    #pragma unroll
    for (int p = 0; p < 4; ++p)
        Wt[(size_t)(n0 + ty + 8 * p) * K + k0 + tx] = (__bf16)t[tx][ty + 8 * p];
}

// ---------------- layernorm: fp32 in, bf16 out ----------------
__global__ __launch_bounds__(256) void ln_kernel(const float* __restrict__ X,
                                                 const float* __restrict__ w,
                                                 const float* __restrict__ b,
                                                 __bf16* __restrict__ Y,
                                                 int src_mul, int src_off) {
    int srow = blockIdx.x * src_mul + src_off;
    const float* xr = X + (size_t)srow * D;
    float v[3];
    float s = 0.f, s2 = 0.f;
    #pragma unroll
    for (int j = 0; j < 3; ++j) {
        v[j] = xr[threadIdx.x + 256 * j];
        s += v[j];
        s2 += v[j] * v[j];
    }
    #pragma unroll
    for (int off = 32; off; off >>= 1) {
        s  += __shfl_xor(s, off);
        s2 += __shfl_xor(s2, off);
    }
    __shared__ float ss[4], ss2[4];
    int wave = threadIdx.x >> 6, lane = threadIdx.x & 63;
    if (lane == 0) { ss[wave] = s; ss2[wave] = s2; }
    __syncthreads();
    s  = ss[0] + ss[1] + ss[2] + ss[3];
    s2 = ss2[0] + ss2[1] + ss2[2] + ss2[3];
    float mu  = s * (1.f / D);
    float var = s2 * (1.f / D) - mu * mu;
    float rs  = rsqrtf(var + EPS);
    __bf16* yr = Y + (size_t)blockIdx.x * D;
    #pragma unroll
    for (int j = 0; j < 3; ++j) {
        int c = threadIdx.x + 256 * j;
        yr[c] = (__bf16)((v[j] - mu) * rs * w[c] + b[c]);
    }
}

// ---- bf16 MFMA GEMM 128x128, BK=32, 3-deep ring + counted vmcnt ------------
template<bool DOGELU>
__global__ __launch_bounds__(256) void gemm_bt(const __bf16* __restrict__ A,
                                               const __bf16* __restrict__ Wt,
                                               const float* __restrict__ bias,
                                               __bf16* __restrict__ Cout,
                                               int N, int K) {
    __shared__ __align__(16) __bf16 sm[24576];   // 3 x (A 4096 | B 4096) = 48 KB
    const int tid  = threadIdx.x;
    const int w    = tid >> 6;
    const int lane = tid & 63;

    // XCD-chunked work remap (nwg % 8 == 0 for all our grids)
    int fid = blockIdx.y * gridDim.x + blockIdx.x;
    const int nwg = gridDim.x * gridDim.y;
    fid = (fid & 7) * (nwg >> 3) + (fid >> 3);
    const int row0 = (fid / gridDim.x) * 128;
    const int col0 = (fid % gridDim.x) * 128;

    const int srow = ((tid >> 6) & 3) * 16 + (tid & 15);
    const int sk   = ((tid >> 4) & 3) * 8;
    const __bf16* gA0 = A  + (size_t)(row0 + srow) * K + sk;
    const __bf16* gA1 = gA0 + (size_t)64 * K;
    const __bf16* gB0 = Wt + (size_t)(col0 + srow) * K + sk;
    const __bf16* gB1 = gB0 + (size_t)64 * K;

    auto stage = [&](int bsel) {
        __bf16* dst = sm + bsel * 8192;
        __builtin_amdgcn_global_load_lds(GAS(gA0), LAS(dst + (size_t)tid * 8), 16, 0, 0);
        __builtin_amdgcn_global_load_lds(GAS(gA1), LAS(dst + (size_t)(tid + 256) * 8), 16, 0, 0);
        __builtin_amdgcn_global_load_lds(GAS(gB0), LAS(dst + 4096 + (size_t)tid * 8), 16, 0, 0);
        __builtin_amdgcn_global_load_lds(GAS(gB1), LAS(dst + 4096 + (size_t)(tid + 256) * 8), 16, 0, 0);
        gA0 += 32; gA1 += 32; gB0 += 32; gB1 += 32;
    };

    const int wr = w >> 1, wc = w & 1;
    const __bf16* rA = sm + wr * 2048 + lane * 8;
    const __bf16* rB = sm + 4096 + wc * 2048 + lane * 8;

    const int nt = K >> 5;          // 24 for K=768
    stage(0); stage(1);             // 8 loads in flight

    v4f acc[4][4] = {};
    for (int t = 0; t < nt; ++t) {
        const int cb = (t % 3) * 8192;
        if (t + 2 < nt) {
            stage((t + 2) % 3);     // 12 in flight
            asm volatile("s_waitcnt vmcnt(8)\n\ts_barrier" ::: "memory");
        } else if (t + 1 < nt) {
            asm volatile("s_waitcnt vmcnt(4)\n\ts_barrier" ::: "memory");
        } else {
            asm volatile("s_waitcnt vmcnt(0)\n\ts_barrier" ::: "memory");
        }
        v8bf af[4], bfr[4];
        #pragma unroll
        for (int i = 0; i < 4; ++i) af[i]  = *(const v8bf*)(rA + cb + i * 512);
        #pragma unroll
        for (int j = 0; j < 4; ++j) bfr[j] = *(const v8bf*)(rB + cb + j * 512);
        #pragma unroll
        for (int i = 0; i < 4; ++i)
            #pragma unroll
            for (int j = 0; j < 4; ++j)
                acc[i][j] = __builtin_amdgcn_mfma_f32_16x16x32_bf16(af[i], bfr[j], acc[i][j], 0, 0, 0);
        SBAR();                     // ring slot (t%3) free for reuse at t+1
    }

    // ---- epilogue: bias/gelu -> bf16 -> LDS (swizzled) -> coalesced stores ----
    const int er = (lane >> 4) * 4;
    const int ec = lane & 15;
    #pragma unroll
    for (int j = 0; j < 4; ++j) {
        const int col = wc * 64 + j * 16 + ec;
        const float bval = bias[col0 + col];
        const int chunk = col >> 3, ce = col & 7;
        #pragma unroll
        for (int i = 0; i < 4; ++i) {
            const int rowb = wr * 64 + i * 16 + er;
            #pragma unroll
            for (int rr = 0; rr < 4; ++rr) {
                float vv = acc[i][j][rr] + bval;
                if (DOGELU) vv = gelu_fast(vv);
                sm[CIDX(rowb + rr, chunk) + ce] = (__bf16)vv;
            }
        }
    }
    __syncthreads();
    #pragma unroll
    for (int c = 0; c < 8; ++c) {
        const int chunkid = tid + c * 256;         // 0..2047
        const int row = chunkid >> 4;
        const int cc  = chunkid & 15;
        *(v8us*)(void*)(Cout + (size_t)(row0 + row) * N + col0 + cc * 8) =
            *(const v8us*)(const void*)(sm + CIDX(row, cc));
    }
}

// ---- bf16 MFMA GEMM 64x64, BK=64, 3-deep ring + counted vmcnt (fp32+res) ---
__global__ __launch_bounds__(256) void gemm64(const __bf16* __restrict__ A,
                                              const __bf16* __restrict__ Wt,
                                              const float* __restrict__ bias,
                                              const float* __restrict__ res,
                                              float* __restrict__ Cout,
                                              int N, int K) {
    __shared__ __align__(16) __bf16 sm[24576];   // 3 x (A 4096 | B 4096) = 48 KB
    const int tid  = threadIdx.x;
    const int w    = tid >> 6;
    const int lane = tid & 63;

    int fid = blockIdx.y * gridDim.x + blockIdx.x;
    const int nwg = gridDim.x * gridDim.y;
    fid = (fid & 7) * (nwg >> 3) + (fid >> 3);
    const int row0 = (fid / gridDim.x) * 64;
    const int col0 = (fid % gridDim.x) * 64;

    const int srow = ((tid >> 7) & 3) * 16 + (tid & 15);
    const int sk   = ((tid >> 4) & 7) * 8;
    const __bf16* gA0 = A  + (size_t)(row0 + srow) * K + sk;
    const __bf16* gA1 = gA0 + (size_t)32 * K;
    const __bf16* gB0 = Wt + (size_t)(col0 + srow) * K + sk;
    const __bf16* gB1 = gB0 + (size_t)32 * K;

    auto stage = [&](int bsel) {
        __bf16* dst = sm + bsel * 8192;
        __builtin_amdgcn_global_load_lds(GAS(gA0), LAS(dst + (size_t)tid * 8), 16, 0, 0);
        __builtin_amdgcn_global_load_lds(GAS(gA1), LAS(dst + (size_t)(tid + 256) * 8), 16, 0, 0);
        __builtin_amdgcn_global_load_lds(GAS(gB0), LAS(dst + 4096 + (size_t)tid * 8), 16, 0, 0);
        __builtin_amdgcn_global_load_lds(GAS(gB1), LAS(dst + 4096 + (size_t)(tid + 256) * 8), 16, 0, 0);
        gA0 += 64; gA1 += 64; gB0 += 64; gB1 += 64;
    };

    const int wr = w >> 1, wc = w & 1;
    const __bf16* rA = sm + wr * 2048 + lane * 8;
    const __bf16* rB = sm + 4096 + wc * 2048 + lane * 8;

    const int nt = K >> 6;          // 12 (proj) / 48 (fcp)
    stage(0); stage(1);

    v4f acc[2][2] = {};
    for (int t = 0; t < nt; ++t) {
        const int cb = (t % 3) * 8192;
        if (t + 2 < nt) {
            stage((t + 2) % 3);
            asm volatile("s_waitcnt vmcnt(8)\n\ts_barrier" ::: "memory");
        } else if (t + 1 < nt) {
            asm volatile("s_waitcnt vmcnt(4)\n\ts_barrier" ::: "memory");
        } else {
            asm volatile("s_waitcnt vmcnt(0)\n\ts_barrier" ::: "memory");
        }
        #pragma unroll
        for (int h = 0; h < 2; ++h) {
            v8bf af[2], bfr[2];
            #pragma unroll
            for (int i = 0; i < 2; ++i) af[i]  = *(const v8bf*)(rA + cb + i * 1024 + h * 512);
            #pragma unroll
            for (int j = 0; j < 2; ++j) bfr[j] = *(const v8bf*)(rB + cb + j * 1024 + h * 512);
            #pragma unroll
            for (int i = 0; i < 2; ++i)
                #pragma unroll
                for (int j = 0; j < 2; ++j)
                    acc[i][j] = __builtin_amdgcn_mfma_f32_16x16x32_bf16(af[i], bfr[j], acc[i][j], 0, 0, 0);
        }
        SBAR();
    }

    // ---- epilogue: acc+bias -> LDS fp32 (swizzled) -> coalesced res+store ----
    float* smf = (float*)sm;        // 64x64 fp32 = 16 KB
    const int er = (lane >> 4) * 4;
    const int ec = lane & 15;
    #pragma unroll
    for (int j = 0; j < 2; ++j) {
        const int col = wc * 32 + j * 16 + ec;
        const float bval = bias[col0 + col];
        #pragma unroll
        for (int i = 0; i < 2; ++i) {
            #pragma unroll
            for (int rr = 0; rr < 4; ++rr) {
                const int row = wr * 32 + i * 16 + er + rr;
                smf[row * 64 + (col ^ ((row & 3) << 4))] = acc[i][j][rr] + bval;
            }
        }
    }
    __syncthreads();
    #pragma unroll
    for (int c = 0; c < 4; ++c) {
        const int chunkid = tid + c * 256;         // 0..1023
        const int row = chunkid >> 4;
        const int c0  = (chunkid & 15) * 4;
        float4 vv = *(const float4*)(smf + row * 64 + (c0 ^ ((row & 3) << 4)));
        const float4 rv = *(const float4*)(res + (size_t)(row0 + row) * N + col0 + c0);
        vv.x += rv.x; vv.y += rv.y; vv.z += rv.z; vv.w += rv.w;
        *(float4*)(Cout + (size_t)(row0 + row) * N + col0 + c0) = vv;
    }
}

// ---------------- MFMA flash attention: 64 q-rows/block, swapped QK^T -------
// K/V double-buffered in LDS: iter kt computes from buf[kt&1] while writing
// the prefetched tile kt+1 into buf[kt&1 ^ 1] -> ONE barrier per k-tile
// (was 2), and the write no longer blocks QK^T issue.
__global__ __launch_bounds__(256) void attn_mfma(const __bf16* __restrict__ qkv,
                                                 __bf16* __restrict__ y) {
    __shared__ __align__(16) __bf16 Qs[4096];
    __shared__ __align__(16) __bf16 Ks[8192];    // 2 x 64x64
    __shared__ __align__(16) __bf16 Vt[8192];    // 2 x 64x64 (transposed)
    __shared__ __align__(16) __bf16 Ps[4][1024];

    const int tid  = threadIdx.x;
    const int w    = tid >> 6;
    const int lane = tid & 63;
    const int quad = lane >> 4;
    const int l4   = lane & 15;

    // XCD-chunked remap
    int fid = blockIdx.x;
    const int nwg = gridDim.x;
    fid = (fid & 7) * (nwg >> 3) + (fid >> 3);

    const int qt = 31 - (fid & 31);              // big tiles first
    const int bh = fid >> 5;
    const int b  = bh / H;
    const int h  = bh - b * H;
    const int q0 = qt * 64;

    const __bf16* base = qkv + (size_t)(b * T) * D3 + h * HD;

    // stage Q tile (64 rows), swizzled
    {
        int c = tid;
        #pragma unroll
        for (int rep = 0; rep < 2; ++rep, c += 256) {
            int row = c >> 3, ch = c & 7;
            v8us v = *(const v8us*)(const void*)(base + (size_t)(q0 + row) * D3 + ch * 8);
            *(v8us*)(void*)(Qs + LIDX(row, ch)) = v;
        }
    }

    const int krow = tid >> 3, kch = tid & 7;
    const int vkp = tid & 31, vdc = tid >> 5;
    const __bf16* kp0 = base + D     + (size_t)krow * D3 + kch * 8;
    const __bf16* kp1 = kp0 + (size_t)32 * D3;
    const __bf16* vp0 = base + 2 * D + (size_t)(2 * vkp) * D3 + vdc * 8;
    const __bf16* vp1 = vp0 + D3;

    v8us kr0 = *(const v8us*)(const void*)kp0;
    v8us kr1 = *(const v8us*)(const void*)kp1;
    v8us vr0 = *(const v8us*)(const void*)vp0;
    v8us vr1 = *(const v8us*)(const void*)vp1;

    const int nt = qt + 1;
    const size_t adv = (size_t)64 * D3;

    // ---- prologue: write tile 0 -> buf 0; prefetch tile 1 into regs --------
    *(v8us*)(void*)(Ks + LIDX(krow, kch))      = kr0;
    *(v8us*)(void*)(Ks + LIDX(krow + 32, kch)) = kr1;
    #pragma unroll
    for (int j = 0; j < 8; ++j) {
        int dim = vdc * 8 + j;
        int idx = dim * 64 + ((((vkp >> 2) ^ (dim & 7))) << 3) + ((vkp & 3) << 1);
        *(unsigned int*)(void*)(Vt + idx) =
            ((unsigned int)vr1[j] << 16) | (unsigned int)vr0[j];
    }
    if (nt > 1) {
        kp0 += adv; kp1 += adv; vp0 += adv; vp1 += adv;
        kr0 = *(const v8us*)(const void*)kp0;
        kr1 = *(const v8us*)(const void*)kp1;
        vr0 = *(const v8us*)(const void*)vp0;
        vr1 = *(const v8us*)(const void*)vp1;
    }
    __syncthreads();

    // hoisted Q fragments
    v8bf qf[2];
    #pragma unroll
    for (int kh = 0; kh < 2; ++kh)
        qf[kh] = *(const v8bf*)(Qs + LIDX(w * 16 + l4, kh * 4 + quad));

    float m_local = -INFINITY;      // running max for q = q0 + w*16 + l4
    v4f o[4] = {};
    v4f sacc = {};                  // softmax denominators via ones-MFMA
    v8bf vones;
    #pragma unroll
    for (int i = 0; i < 8; ++i) vones[i] = (__bf16)1.0f;

    const int qrow = q0 + w * 16 + l4;

    for (int kt = 0; kt < nt; ++kt) {
        const int cur = (kt & 1) << 12;      // 0 / 4096 elements
        const int nxt = cur ^ 4096;
        const int k0 = kt * 64;

        // ---- S^T = K Q^T : lane holds keys (jb*16 + quad*4 + rg) for q=l4 ----
        v4f s[4] = {};
        __builtin_amdgcn_s_setprio(1);
        #pragma unroll
        for (int kh = 0; kh < 2; ++kh) {
            #pragma unroll
            for (int jb = 0; jb < 4; ++jb) {
                v8bf bk = *(const v8bf*)(Ks + cur + LIDX(jb * 16 + l4, kh * 4 + quad));
                s[jb] = __builtin_amdgcn_mfma_f32_16x16x32_bf16(bk, qf[kh], s[jb], 0, 0, 0);
            }
        }
        __builtin_amdgcn_s_setprio(0);

        // ---- write prefetched tile kt+1 -> buf nxt; issue loads for kt+2 ----
        if (kt + 1 < nt) {
            *(v8us*)(void*)(Ks + nxt + LIDX(krow, kch))      = kr0;
            *(v8us*)(void*)(Ks + nxt + LIDX(krow + 32, kch)) = kr1;
            #pragma unroll
            for (int j = 0; j < 8; ++j) {
                int dim = vdc * 8 + j;
                int idx = dim * 64 + ((((vkp >> 2) ^ (dim & 7))) << 3) + ((vkp & 3) << 1);
                *(unsigned int*)(void*)(Vt + nxt + idx) =
                    ((unsigned int)vr1[j] << 16) | (unsigned int)vr0[j];
            }
            if (kt + 2 < nt) {
                kp0 += adv; kp1 += adv; vp0 += adv; vp1 += adv;
                kr0 = *(const v8us*)(const void*)kp0;
                kr1 = *(const v8us*)(const void*)kp1;
                vr0 = *(const v8us*)(const void*)vp0;
                vr1 = *(const v8us*)(const void*)vp1;
            }
        }

        // ---- online softmax, lane-local row ----
        float sv[4][4];
        float mx = -INFINITY;
        #pragma unroll
        for (int jb = 0; jb < 4; ++jb) {
            #pragma unroll
            for (int rg = 0; rg < 4; ++rg) {
                float vvv = s[jb][rg] * 0.125f;
                if (k0 + jb * 16 + quad * 4 + rg > qrow) vvv = -INFINITY;
                sv[jb][rg] = vvv;
                mx = fmaxf(mx, vvv);
            }
        }
        mx = fmaxf(mx, __shfl_xor(mx, 16));
        mx = fmaxf(mx, __shfl_xor(mx, 32));
        // defer-max: rescale only when some lane's max grew past m_local + 8
        if (!__all(mx <= m_local + 8.f)) {
            const float mnew    = fmaxf(m_local, mx);
            const float alpha_l = __expf(m_local - mnew);
            m_local = mnew;
            float a4[4];
            #pragma unroll
            for (int r = 0; r < 4; ++r) a4[r] = __shfl(alpha_l, quad * 4 + r);
            #pragma unroll
            for (int r = 0; r < 4; ++r) {
                sacc[r] *= a4[r];
                #pragma unroll
                for (int db = 0; db < 4; ++db) o[db][r] *= a4[r];
            }
        }
        // ---- P -> per-wave LDS (packed b64 stores, swizzled) ----
        #pragma unroll
        for (int jb = 0; jb < 4; ++jb) {
            v4bf pk;
            #pragma unroll
            for (int rg = 0; rg < 4; ++rg)
                pk[rg] = (__bf16)__expf(sv[jb][rg] - m_local);
            *(v4bf*)(void*)(&Ps[w][LIDX(l4, jb * 2 + (quad >> 1)) + ((quad & 1) << 2)]) = pk;
        }
        // ---- O += P V ; denom += P 1 ----
        __builtin_amdgcn_s_setprio(1);
        #pragma unroll
        for (int kh = 0; kh < 2; ++kh) {
            v8bf ap = *(const v8bf*)(&Ps[w][LIDX(l4, kh * 4 + quad)]);
            sacc = __builtin_amdgcn_mfma_f32_16x16x32_bf16(ap, vones, sacc, 0, 0, 0);
            #pragma unroll
            for (int db = 0; db < 4; ++db) {
                v8bf bv = *(const v8bf*)(Vt + cur + LIDX(db * 16 + l4, kh * 4 + quad));
                o[db] = __builtin_amdgcn_mfma_f32_16x16x32_bf16(ap, bv, o[db], 0, 0, 0);
            }
        }
        __builtin_amdgcn_s_setprio(0);
        if (kt + 1 < nt) __syncthreads();    // single barrier per k-tile
    }

    // ---- epilogue ----
    #pragma unroll
    for (int db = 0; db < 4; ++db) {
        #pragma unroll
        for (int r = 0; r < 4; ++r) {
            const int q = q0 + w * 16 + quad * 4 + r;
            y[(size_t)(b * T + q) * D + h * HD + db * 16 + l4] =
                (__bf16)(o[db][r] / sacc[r]);
        }
    }
}

// ---------------- lm head: both batch rows per wte pass ---------------------
__global__ __launch_bounds__(256) void logits_kernel(const __bf16* __restrict__ xf,
                                                     const float* __restrict__ wte,
                                                     float* __restrict__ out) {
    int wave = threadIdx.x >> 6;
    int lane = threadIdx.x & 63;
    int v = blockIdx.x * 4 + wave;
    if (v >= V) return;
    const float4* wr = (const float4*)(wte + (size_t)v * D);   // 192 chunks
    const v4bf*   x0 = (const v4bf*)(xf);
    const v4bf*   x1 = (const v4bf*)(xf + D);
    float s0 = 0.f, s1 = 0.f;
    #pragma unroll
    for (int j = 0; j < 3; ++j) {
        float4 wv = wr[lane + 64 * j];
        v4bf a0 = x0[lane + 64 * j];
        v4bf a1 = x1[lane + 64 * j];
        s0 = fmaf(wv.x, (float)a0[0], s0); s0 = fmaf(wv.y, (float)a0[1], s0);
        s0 = fmaf(wv.z, (float)a0[2], s0); s0 = fmaf(wv.w, (float)a0[3], s0);
        s1 = fmaf(wv.x, (float)a1[0], s1); s1 = fmaf(wv.y, (float)a1[1], s1);
        s1 = fmaf(wv.z, (float)a1[2], s1); s1 = fmaf(wv.w, (float)a1[3], s1);
    }
    #pragma unroll
    for (int off = 32; off; off >>= 1) {
        s0 += __shfl_xor(s0, off);
        s1 += __shfl_xor(s1, off);
    }
    if (lane == 0) { out[v] = s0; out[V + v] = s1; }
}

extern "C" void kernel_launch(void* const* d_in, const int* in_sizes, int n_in,
                              void* d_out, int out_size, void* d_ws, size_t ws_size,
                              hipStream_t stream) {
    const int*   idx    = (const int*)  d_in[0];
    const float* wte    = (const float*)d_in[1];
    const float* wpe    = (const float*)d_in[2];
    const float* ln1_w  = (const float*)d_in[3];
    const float* ln1_b  = (const float*)d_in[4];
    const float* attn_w = (const float*)d_in[5];
    const float* attn_b = (const float*)d_in[6];
    const float* proj_w = (const float*)d_in[7];
    const float* proj_b = (const float*)d_in[8];
    const float* ln2_w  = (const float*)d_in[9];
    const float* ln2_b  = (const float*)d_in[10];
    const float* fc_w   = (const float*)d_in[11];
    const float* fc_b   = (const float*)d_in[12];
    const float* fcp_w  = (const float*)d_in[13];
    const float* fcp_b  = (const float*)d_in[14];
    const float* lnf_w  = (const float*)d_in[15];
    const float* lnf_b  = (const float*)d_in[16];
    float* out = (float*)d_out;

    char* ws = (char*)d_ws;
    float*  x    = (float*)ws;  ws += (size_t)NTOK * D  * 4;       // residual stream fp32
    __bf16* qkvb = (__bf16*)ws;                                     // [NTOK,3D] bf16
    __bf16* gb   = (__bf16*)ws; ws += (size_t)NTOK * D4 * 2;       // [NTOK,4D] bf16 (alias)
    __bf16* hb   = (__bf16*)ws; ws += (size_t)NTOK * D  * 2;       // ln out
    __bf16* yb   = (__bf16*)ws; ws += (size_t)NTOK * D  * 2;       // attn out
    __bf16* awt  = (__bf16*)ws; ws += (size_t)L * D3 * D   * 2;    // attn_w^T (all layers)
    __bf16* pwt  = (__bf16*)ws; ws += (size_t)L * D  * D   * 2;    // proj_w^T
    __bf16* fwt  = (__bf16*)ws; ws += (size_t)L * D4 * D   * 2;    // fc_w^T
    __bf16* fpwt = (__bf16*)ws; ws += (size_t)L * D  * D4  * 2;    // fcp_w^T
    __bf16* xf   = (__bf16*)ws; ws += (size_t)B * D    * 2;

    // embed + all 16 weight transposes in one dispatch
    prep_kernel<<<3072 + 6912 * L, 256, 0, stream>>>(idx, wte, wpe, x,
                                                     attn_w, proj_w, fc_w, fcp_w,
                                                     awt, pwt, fwt, fpwt);

    for (int l = 0; l < L; ++l) {
        const float* l1w = ln1_w + l * D;
        const float* l1b = ln1_b + l * D;
        const float* ab  = attn_b + l * D3;
        const float* pb  = proj_b + l * D;
        const float* l2w = ln2_w + l * D;
        const float* l2b = ln2_b + l * D;
        const float* fb  = fc_b + l * D4;
        const float* fpb = fcp_b + l * D;
        const __bf16* awl  = awt  + (size_t)l * D3 * D;
        const __bf16* pwl  = pwt  + (size_t)l * D  * D;
        const __bf16* fwl  = fwt  + (size_t)l * D4 * D;
        const __bf16* fpwl = fpwt + (size_t)l * D  * D4;

        // h = ln1(x)
        ln_kernel<<<NTOK, 256, 0, stream>>>(x, l1w, l1b, hb, 1, 0);
        // qkv = h @ aw + ab  [bf16]
        gemm_bt<false><<<dim3(D3 / 128, NTOK / 128), 256, 0, stream>>>(
            hb, awl, ab, qkvb, D3, D);
        // y = flash-attention(qkv)  [bf16]  (64-row q-tiles: 768 blocks)
        attn_mfma<<<B * H * (T / 64), 256, 0, stream>>>(qkvb, yb);
        // x = x + y @ pw + pb   (64x64 tiles: 768 blocks = 3/CU)
        gemm64<<<dim3(D / 64, NTOK / 64), 256, 0, stream>>>(
            yb, pwl, pb, x, x, D, D);
        // h = ln2(x)
        ln_kernel<<<NTOK, 256, 0, stream>>>(x, l2w, l2b, hb, 1, 0);
        // gb = gelu(h @ fw + fb)  [bf16]
        gemm_bt<true><<<dim3(D4 / 128, NTOK / 128), 256, 0, stream>>>(
            hb, fwl, fb, gb, D4, D);
        // x = x + gb @ fpw + fpb  (64x64 tiles)
        gemm64<<<dim3(D / 64, NTOK / 64), 256, 0, stream>>>(
            gb, fpwl, fpb, x, x, D, D4);
    }

    ln_kernel<<<B, 256, 0, stream>>>(x, lnf_w, lnf_b, xf, T, T - 1);
    logits_kernel<<<(V + 3) / 4, 256, 0, stream>>>(xf, wte, out);
}